// Round 2
// baseline (27720.450 us; speedup 1.0000x reference)
//
#include <hip/hip_runtime.h>
#include <hip/hip_bf16.h>
#include <math.h>

#define B   64
#define T   1000
#define INP 64
#define HID 512
#define ACT 2

#define NSLICE 4                    // column slices per row-group (sync group size)
#define MROWS  2                    // batch rows per block
#define NGROUP (B / MROWS)          // 32 row-groups
#define NBLOCKS (NGROUP * NSLICE)   // 128 blocks — co-resident even at 1 blk/CU
#define COLS   (HID / NSLICE)       // 128 cols per block
#define TCOLS  16                   // cols per wave (one MFMA n-tile)

typedef __attribute__((ext_vector_type(8))) short short8;   // 8 bf16
typedef __attribute__((ext_vector_type(4))) float floatx4;  // MFMA C/D

// ---------------------------------------------------------------------------
// K0: init — hn (fp32) -> bf16 into h_ex parity-1 buffer; zero sync counters.
// (d_ws is re-poisoned 0xAA before every launch, so this must run every call.)
// ---------------------------------------------------------------------------
__global__ __launch_bounds__(256) void init_kernel(
    const float* __restrict__ hn, unsigned short* __restrict__ h_ex,
    int* __restrict__ cnt) {
  const int i = blockIdx.x * 256 + threadIdx.x;  // 0 .. B*HID-1
  const float v = hn[i];
  __hip_bfloat16 b = __float2bfloat16(v);
  h_ex[(long)B * HID + i] = *reinterpret_cast<unsigned short*>(&b);
  if (i < NGROUP * 2) cnt[i] = 0;
}

// ---------------------------------------------------------------------------
// K1: xproj[b,t,:] = inp[b,t,:] @ W_ih  -> rnn slab (overwritten by h later)
// ---------------------------------------------------------------------------
__global__ __launch_bounds__(256) void xproj_kernel(
    const float* __restrict__ inp, const float* __restrict__ W_ih,
    float* __restrict__ rnn) {
  __shared__ float xin[16 * INP];
  const int tid = threadIdx.x;
  const long r0 = (long)blockIdx.x * 16;

  const float4* inp4 = (const float4*)(inp + r0 * INP);
  ((float4*)xin)[tid] = inp4[tid];
  __syncthreads();

  const int j = tid, j2 = tid + 256;
  float acc0[16], acc1[16];
#pragma unroll
  for (int r = 0; r < 16; ++r) { acc0[r] = 0.f; acc1[r] = 0.f; }

  for (int i = 0; i < INP; ++i) {
    const float w0 = W_ih[i * HID + j];
    const float w1 = W_ih[i * HID + j2];
#pragma unroll
    for (int r = 0; r < 16; ++r) {
      const float x = xin[r * INP + i];
      acc0[r] = fmaf(x, w0, acc0[r]);
      acc1[r] = fmaf(x, w1, acc1[r]);
    }
  }
#pragma unroll
  for (int r = 0; r < 16; ++r) {
    rnn[(r0 + r) * HID + j]  = acc0[r];
    rnn[(r0 + r) * HID + j2] = acc1[r];
  }
}

// ---------------------------------------------------------------------------
// K2: recurrence. W_hh lives in VGPRs (bf16 B-frags) for all 1000 steps.
// 128 blocks = 32 row-pairs x 4 col-slices; per-step 4-block flag sync.
// Group blocks {g, g+32, g+64, g+96} share bid%8 -> same XCD (locality only).
// ---------------------------------------------------------------------------
__global__ __launch_bounds__(512) void rnn_mfma(
    const float* __restrict__ W_hh, float* __restrict__ rnn,
    float* __restrict__ hn_out, unsigned short* __restrict__ h_ex,
    int* __restrict__ cnt) {
  const int tid  = threadIdx.x;
  const int lane = tid & 63;
  const int w    = tid >> 6;          // wave 0..7
  const int g    = blockIdx.x & 31;   // row-group (same-XCD grouping)
  const int s    = blockIdx.x >> 5;   // col-slice 0..3
  const int r0   = g * MROWS;
  const int n_base = s * COLS + w * TCOLS;

  const int lm = lane & 15;           // MFMA m/n lane index
  const int lq = lane >> 4;           // quad 0..3 -> k-subchunk
  const int cc = n_base + lm;         // this lane's output column

  // ---- one-time: W_hh column slice -> bf16 B-frags in registers (64 VGPRs)
  // B-frag layout: lane holds B[k = kt*32 + lq*8 + i][n = lm]
  short8 bfrag[16];
#pragma unroll
  for (int kt = 0; kt < 16; ++kt) {
    short8 f;
#pragma unroll
    for (int i = 0; i < 8; ++i) {
      const int k = kt * 32 + lq * 8 + i;
      __hip_bfloat16 hb = __float2bfloat16(W_hh[k * HID + cc]);
      f[i] = *reinterpret_cast<short*>(&hb);
    }
    bfrag[kt] = f;
  }

  // A-frag source row (M=2 real rows, duplicated into m=2..15; those C rows
  // are don't-care). lane reads h[r0 + (lm&1)][kt*32 + lq*8 .. +8] as bf16x8.
  const int arow_off = (r0 + (lm & 1)) * HID + lq * 8;
  int* const my_cnt_base = cnt + g * 2;

  for (int t = 0; t < T; ++t) {
    const int p_prev = (t + 1) & 1;   // parity holding h_{t-1} (t=0 -> init buf)

    if (t > 0) {
      const int target = NSLICE * ((t + 1) >> 1);
      int guard = 0;
      while (__hip_atomic_load(my_cnt_base + p_prev, __ATOMIC_RELAXED,
                               __HIP_MEMORY_SCOPE_AGENT) < target) {
        __builtin_amdgcn_s_sleep(1);
        if (++guard > (1 << 26)) break;   // never hang the harness
      }
      (void)__hip_atomic_load(my_cnt_base + p_prev, __ATOMIC_ACQUIRE,
                              __HIP_MEMORY_SCOPE_AGENT);  // L1 inv / ordering
    }

    // prefetch xproj early (independent of h exchange)
    const long ro0 = ((long)r0 * T + t) * HID + cc;
    const long ro1 = ((long)(r0 + 1) * T + t) * HID + cc;
    const float xp0 = rnn[ro0];
    const float xp1 = rnn[ro1];

    const unsigned short* ap =
        h_ex + (long)p_prev * B * HID + arow_off;
    floatx4 ca = {0.f, 0.f, 0.f, 0.f};
    floatx4 cb = {0.f, 0.f, 0.f, 0.f};
#pragma unroll
    for (int kt = 0; kt < 16; kt += 2) {
      short8 a0 = *(const short8*)(ap + kt * 32);
      short8 a1 = *(const short8*)(ap + (kt + 1) * 32);
      ca = __builtin_amdgcn_mfma_f32_16x16x32_bf16(a0, bfrag[kt],     ca, 0, 0, 0);
      cb = __builtin_amdgcn_mfma_f32_16x16x32_bf16(a1, bfrag[kt + 1], cb, 0, 0, 0);
    }

    if (lq == 0) {  // C layout: col = lane&15, row = (lane>>4)*4 + reg
      const float z0 = ca[0] + cb[0] + xp0;
      const float z1 = ca[1] + cb[1] + xp1;
      const float h0 = 1.f / (1.f + __expf(-z0));
      const float h1 = 1.f / (1.f + __expf(-z1));
      rnn[ro0] = h0;                   // overwrite xproj with h (output 3)
      rnn[ro1] = h1;
      unsigned short* hw = h_ex + (long)(t & 1) * B * HID;
      __hip_bfloat16 b0 = __float2bfloat16(h0);
      __hip_bfloat16 b1 = __float2bfloat16(h1);
      hw[r0 * HID + cc]       = *reinterpret_cast<unsigned short*>(&b0);
      hw[(r0 + 1) * HID + cc] = *reinterpret_cast<unsigned short*>(&b1);
      if (t == T - 1) {
        hn_out[r0 * HID + cc]       = h0;
        hn_out[(r0 + 1) * HID + cc] = h1;
      }
    }

    __threadfence();                   // my stores device-visible
    __syncthreads();                   // all waves' stores fenced
    if (tid == 0)
      __hip_atomic_fetch_add(cnt + g * 2 + (t & 1), 1, __ATOMIC_RELEASE,
                             __HIP_MEMORY_SCOPE_AGENT);
  }
}

// ---------------------------------------------------------------------------
// K3: out[b,t,:] = sigmoid(rnn[b,t,:] @ W_fc + b_fc)
// ---------------------------------------------------------------------------
__global__ __launch_bounds__(256) void fc_kernel(
    const float* __restrict__ rnn, const float* __restrict__ W_fc,
    const float* __restrict__ b_fc, float* __restrict__ out) {
  const int lane = threadIdx.x & 63;
  const int wid  = threadIdx.x >> 6;
  const long row = (long)blockIdx.x * 4 + wid;

  const float4* __restrict__ hrow = (const float4*)(rnn + row * HID);
  const float4* __restrict__ Wfc4 = (const float4*)W_fc;

  float a0 = 0.f, a1 = 0.f;
#pragma unroll
  for (int u = 0; u < 2; ++u) {
    const float4 hv = hrow[lane * 2 + u];
    const int j0 = lane * 8 + u * 4;
    const float4 wA = Wfc4[(j0 >> 1)];
    const float4 wB = Wfc4[(j0 >> 1) + 1];
    a0 += hv.x * wA.x + hv.y * wA.z + hv.z * wB.x + hv.w * wB.z;
    a1 += hv.x * wA.y + hv.y * wA.w + hv.z * wB.y + hv.w * wB.w;
  }
#pragma unroll
  for (int off = 32; off > 0; off >>= 1) {
    a0 += __shfl_down(a0, off, 64);
    a1 += __shfl_down(a1, off, 64);
  }
  if (lane == 0) {
    out[row * 2 + 0] = 1.f / (1.f + __expf(-(a0 + b_fc[0])));
    out[row * 2 + 1] = 1.f / (1.f + __expf(-(a1 + b_fc[1])));
  }
}

// ---------------------------------------------------------------------------
extern "C" void kernel_launch(void* const* d_in, const int* in_sizes, int n_in,
                              void* d_out, int out_size, void* d_ws,
                              size_t ws_size, hipStream_t stream) {
  const float* inp  = (const float*)d_in[0];
  const float* hn   = (const float*)d_in[1];
  const float* W_hh = (const float*)d_in[2];
  const float* W_ih = (const float*)d_in[3];
  const float* W_fc = (const float*)d_in[4];
  const float* b_fc = (const float*)d_in[5];

  float* out    = (float*)d_out;              // [B,T,ACT]
  float* hn_out = out + (long)B * T * ACT;    // [1,B,HID]
  float* rnn    = hn_out + (long)B * HID;     // [B,T,HID]

  // workspace: h_ex[2][B][HID] bf16 (128 KB) + cnt[NGROUP][2] (256 B)
  unsigned short* h_ex = (unsigned short*)d_ws;
  int* cnt = (int*)((char*)d_ws + 2L * B * HID * sizeof(unsigned short));

  hipLaunchKernelGGL(init_kernel, dim3((B * HID) / 256), dim3(256), 0, stream,
                     hn, h_ex, cnt);
  hipLaunchKernelGGL(xproj_kernel, dim3((B * T) / 16), dim3(256), 0, stream,
                     inp, W_ih, rnn);
  hipLaunchKernelGGL(rnn_mfma, dim3(NBLOCKS), dim3(512), 0, stream,
                     W_hh, rnn, hn_out, h_ex, cnt);
  hipLaunchKernelGGL(fc_kernel, dim3((B * T) / 4), dim3(256), 0, stream,
                     rnn, W_fc, b_fc, out);
}

// Round 3
// 1878.180 us; speedup vs baseline: 14.7592x; 14.7592x over previous
//
#include <hip/hip_runtime.h>
#include <hip/hip_bf16.h>
#include <stdint.h>
#include <math.h>

#define B   64
#define T   1000
#define INP 64
#define HID 512
#define ACT 2

#define NSLICE 4                    // column slices per row-group
#define MROWS  2                    // batch rows per block
#define NGROUP (B / MROWS)          // 32 row-groups
#define NBLOCKS (NGROUP * NSLICE)   // 128 blocks — co-resident even at 1 blk/CU
#define COLS   (HID / NSLICE)       // 128 cols per block

typedef __attribute__((ext_vector_type(8))) short short8;   // 8 bf16
typedef __attribute__((ext_vector_type(4))) float floatx4;  // MFMA C/D

// ---------------------------------------------------------------------------
// K0: init — hn (fp32) -> tagged bf16 words into h_ex parity-1 buffer
// (tag 0 = "h_{-1}"). Parity-0 gets a never-matching tag (d_ws is poisoned
// 0xAA each call, which also never matches, but be explicit).
// Tagged word format: (bf16 bits << 16) | (step_tag & 0xFFFF); h_t has tag t+1.
// ---------------------------------------------------------------------------
__global__ __launch_bounds__(256) void init_kernel(
    const float* __restrict__ hn, uint32_t* __restrict__ h_ex) {
  const int i = blockIdx.x * 256 + threadIdx.x;  // 0 .. B*HID-1
  __hip_bfloat16 b = __float2bfloat16(hn[i]);
  const uint32_t hb = *reinterpret_cast<unsigned short*>(&b);
  h_ex[(size_t)B * HID + i] = (hb << 16) | 0u;   // parity 1, tag 0
  h_ex[i] = 0xFFFEu;                             // parity 0, non-matching tag
}

// ---------------------------------------------------------------------------
// K1: xproj[b,t,:] = inp[b,t,:] @ W_ih  -> rnn slab (overwritten by h later)
// ---------------------------------------------------------------------------
__global__ __launch_bounds__(256) void xproj_kernel(
    const float* __restrict__ inp, const float* __restrict__ W_ih,
    float* __restrict__ rnn) {
  __shared__ float xin[16 * INP];
  const int tid = threadIdx.x;
  const long r0 = (long)blockIdx.x * 16;

  const float4* inp4 = (const float4*)(inp + r0 * INP);
  ((float4*)xin)[tid] = inp4[tid];
  __syncthreads();

  const int j = tid, j2 = tid + 256;
  float acc0[16], acc1[16];
#pragma unroll
  for (int r = 0; r < 16; ++r) { acc0[r] = 0.f; acc1[r] = 0.f; }

  for (int i = 0; i < INP; ++i) {
    const float w0 = W_ih[i * HID + j];
    const float w1 = W_ih[i * HID + j2];
#pragma unroll
    for (int r = 0; r < 16; ++r) {
      const float x = xin[r * INP + i];
      acc0[r] = fmaf(x, w0, acc0[r]);
      acc1[r] = fmaf(x, w1, acc1[r]);
    }
  }
#pragma unroll
  for (int r = 0; r < 16; ++r) {
    rnn[(r0 + r) * HID + j]  = acc0[r];
    rnn[(r0 + r) * HID + j2] = acc1[r];
  }
}

// ---------------------------------------------------------------------------
// K2: recurrence. W_hh register-resident (bf16 B-frags, AGPR-backed) for all
// 1000 steps. Fence-free exchange: relaxed agent-scope atomic words carrying
// (bf16 h | step tag). Correctness is placement-independent (LLC-coherent).
// ---------------------------------------------------------------------------
__global__ __launch_bounds__(512) void rnn_mfma(
    const float* __restrict__ W_hh, float* __restrict__ rnn,
    float* __restrict__ hn_out, uint32_t* __restrict__ h_ex) {
  __shared__ __align__(16) unsigned short hl[2][MROWS][HID];  // 4 KB

  const int tid  = threadIdx.x;
  const int lane = tid & 63;
  const int w    = tid >> 6;              // wave 0..7
  const int g    = blockIdx.x & (NGROUP - 1);
  const int s    = blockIdx.x >> 5;       // col-slice 0..3
  const int r0   = g * MROWS;
  const int n_base = s * COLS + w * 16;

  const int lm = lane & 15;               // MFMA m/n lane index
  const int lq = lane >> 4;               // quad 0..3 -> k-subchunk
  const int cc = n_base + lm;             // this lane's output column

  // ---- one-time: W_hh column slice -> bf16 B-frags (lane holds
  // B[k = kt*32 + lq*8 + i][n = lm]); ~64 regs, compiler places in AGPRs.
  short8 bfrag[16];
#pragma unroll
  for (int kt = 0; kt < 16; ++kt) {
    short8 f;
#pragma unroll
    for (int i = 0; i < 8; ++i) {
      const int k = kt * 32 + lq * 8 + i;
      __hip_bfloat16 hb = __float2bfloat16(W_hh[k * HID + cc]);
      f[i] = *reinterpret_cast<short*>(&hb);
    }
    bfrag[kt] = f;
  }

  const int arow = lm & 1;                // A row duplication (M=2 real rows)

  for (int t = 0; t < T; ++t) {
    const int p = (t + 1) & 1;            // parity holding h_{t-1}

    // xproj loads for this step — independent of exchange, issue first
    const long ro0 = ((long)r0 * T + t) * HID + cc;
    const long ro1 = ((long)(r0 + 1) * T + t) * HID + cc;
    const float xp0 = rnn[ro0];
    const float xp1 = rnn[ro1];

    // ---- poll tagged words (thread tid owns (row0,col tid),(row1,col tid))
    uint32_t* src = h_ex + (size_t)p * B * HID + (size_t)r0 * HID + tid;
    const uint32_t want = (uint32_t)t & 0xFFFFu;  // h_{t-1} carries tag t
    uint32_t w0v = 0, w1v = 0;
    bool d0 = false, d1 = false;
    int guard = 0;
    do {
      if (!d0) {
        uint32_t v = __hip_atomic_load(src, __ATOMIC_RELAXED,
                                       __HIP_MEMORY_SCOPE_AGENT);
        if ((v & 0xFFFFu) == want) { w0v = v; d0 = true; }
      }
      if (!d1) {
        uint32_t v = __hip_atomic_load(src + HID, __ATOMIC_RELAXED,
                                       __HIP_MEMORY_SCOPE_AGENT);
        if ((v & 0xFFFFu) == want) { w1v = v; d1 = true; }
      }
      if (d0 && d1) break;
      __builtin_amdgcn_s_sleep(1);
    } while (++guard < (1 << 22));        // never hang the harness

    hl[p][0][tid] = (unsigned short)(w0v >> 16);
    hl[p][1][tid] = (unsigned short)(w1v >> 16);
    __syncthreads();                      // one barrier/step (LDS parity-dbuf)

    // ---- 16 MFMA over k, 2 independent chains
    floatx4 ca = {0.f, 0.f, 0.f, 0.f};
    floatx4 cb = {0.f, 0.f, 0.f, 0.f};
    const unsigned short* ap = &hl[p][arow][lq * 8];
#pragma unroll
    for (int kt = 0; kt < 16; kt += 2) {
      short8 a0 = *(const short8*)(ap + kt * 32);
      short8 a1 = *(const short8*)(ap + (kt + 1) * 32);
      ca = __builtin_amdgcn_mfma_f32_16x16x32_bf16(a0, bfrag[kt],     ca, 0, 0, 0);
      cb = __builtin_amdgcn_mfma_f32_16x16x32_bf16(a1, bfrag[kt + 1], cb, 0, 0, 0);
    }

    if (lq == 0) {  // C layout: col = lane&15, row = (lane>>4)*4 + reg
      const float z0 = ca[0] + cb[0] + xp0;
      const float z1 = ca[1] + cb[1] + xp1;
      const float h0 = 1.f / (1.f + __expf(-z0));
      const float h1 = 1.f / (1.f + __expf(-z1));
      rnn[ro0] = h0;                       // overwrite xproj with h (output 3)
      rnn[ro1] = h1;
      __hip_bfloat16 b0 = __float2bfloat16(h0);
      __hip_bfloat16 b1 = __float2bfloat16(h1);
      const uint32_t tag = (uint32_t)(t + 1) & 0xFFFFu;
      uint32_t* dst = h_ex + (size_t)(t & 1) * B * HID + (size_t)r0 * HID + cc;
      __hip_atomic_store(dst,
          ((uint32_t)*reinterpret_cast<unsigned short*>(&b0) << 16) | tag,
          __ATOMIC_RELAXED, __HIP_MEMORY_SCOPE_AGENT);
      __hip_atomic_store(dst + HID,
          ((uint32_t)*reinterpret_cast<unsigned short*>(&b1) << 16) | tag,
          __ATOMIC_RELAXED, __HIP_MEMORY_SCOPE_AGENT);
      if (t == T - 1) {
        hn_out[r0 * HID + cc]       = h0;
        hn_out[(r0 + 1) * HID + cc] = h1;
      }
    }
  }
}

// ---------------------------------------------------------------------------
// K3: out[b,t,:] = sigmoid(rnn[b,t,:] @ W_fc + b_fc)
// ---------------------------------------------------------------------------
__global__ __launch_bounds__(256) void fc_kernel(
    const float* __restrict__ rnn, const float* __restrict__ W_fc,
    const float* __restrict__ b_fc, float* __restrict__ out) {
  const int lane = threadIdx.x & 63;
  const int wid  = threadIdx.x >> 6;
  const long row = (long)blockIdx.x * 4 + wid;

  const float4* __restrict__ hrow = (const float4*)(rnn + row * HID);
  const float4* __restrict__ Wfc4 = (const float4*)W_fc;

  float a0 = 0.f, a1 = 0.f;
#pragma unroll
  for (int u = 0; u < 2; ++u) {
    const float4 hv = hrow[lane * 2 + u];
    const int j0 = lane * 8 + u * 4;
    const float4 wA = Wfc4[(j0 >> 1)];
    const float4 wB = Wfc4[(j0 >> 1) + 1];
    a0 += hv.x * wA.x + hv.y * wA.z + hv.z * wB.x + hv.w * wB.z;
    a1 += hv.x * wA.y + hv.y * wA.w + hv.z * wB.y + hv.w * wB.w;
  }
#pragma unroll
  for (int off = 32; off > 0; off >>= 1) {
    a0 += __shfl_down(a0, off, 64);
    a1 += __shfl_down(a1, off, 64);
  }
  if (lane == 0) {
    out[row * 2 + 0] = 1.f / (1.f + __expf(-(a0 + b_fc[0])));
    out[row * 2 + 1] = 1.f / (1.f + __expf(-(a1 + b_fc[1])));
  }
}

// ---------------------------------------------------------------------------
extern "C" void kernel_launch(void* const* d_in, const int* in_sizes, int n_in,
                              void* d_out, int out_size, void* d_ws,
                              size_t ws_size, hipStream_t stream) {
  const float* inp  = (const float*)d_in[0];
  const float* hn   = (const float*)d_in[1];
  const float* W_hh = (const float*)d_in[2];
  const float* W_ih = (const float*)d_in[3];
  const float* W_fc = (const float*)d_in[4];
  const float* b_fc = (const float*)d_in[5];

  float* out    = (float*)d_out;              // [B,T,ACT]
  float* hn_out = out + (long)B * T * ACT;    // [1,B,HID]
  float* rnn    = hn_out + (long)B * HID;     // [B,T,HID]

  // workspace: h_ex[2][B][HID] tagged uint32 words (256 KB)
  uint32_t* h_ex = (uint32_t*)d_ws;

  hipLaunchKernelGGL(init_kernel, dim3((B * HID) / 256), dim3(256), 0, stream,
                     hn, h_ex);
  hipLaunchKernelGGL(xproj_kernel, dim3((B * T) / 16), dim3(256), 0, stream,
                     inp, W_ih, rnn);
  hipLaunchKernelGGL(rnn_mfma, dim3(NBLOCKS), dim3(512), 0, stream,
                     W_hh, rnn, hn_out, h_ex);
  hipLaunchKernelGGL(fc_kernel, dim3((B * T) / 4), dim3(256), 0, stream,
                     rnn, W_fc, b_fc, out);
}

// Round 4
// 1659.506 us; speedup vs baseline: 16.7040x; 1.1318x over previous
//
#include <hip/hip_runtime.h>
#include <hip/hip_bf16.h>
#include <stdint.h>
#include <math.h>

#define B   64
#define T   1000
#define INP 64
#define HID 512
#define ACT 2

#define NSLICE 4                    // column slices per row-group
#define MROWS  2                    // batch rows per block
#define NGROUP (B / MROWS)          // 32 row-groups
#define NBLOCKS (NGROUP * NSLICE)   // 128 blocks — co-resident even at 1 blk/CU
#define COLS   (HID / NSLICE)       // 128 cols per block
#define HLPAD  544                  // row stride (shorts): bank shift 16/row -> 0 conflicts

typedef __attribute__((ext_vector_type(8))) short short8;   // 8 bf16
typedef __attribute__((ext_vector_type(4))) float floatx4;  // MFMA C/D

// ---------------------------------------------------------------------------
// K0: init — hn (fp32) -> tagged bf16 words, parity-1 buffer, tag 0 (=h_{-1}).
// Tagged word: (bf16 bits << 16) | (step_tag & 0xFFFF); h_t carries tag t+1.
// ---------------------------------------------------------------------------
__global__ __launch_bounds__(256) void init_kernel(
    const float* __restrict__ hn, uint32_t* __restrict__ h_ex) {
  const int i = blockIdx.x * 256 + threadIdx.x;  // 0 .. B*HID-1
  __hip_bfloat16 b = __float2bfloat16(hn[i]);
  const uint32_t hb = *reinterpret_cast<unsigned short*>(&b);
  h_ex[(size_t)B * HID + i] = (hb << 16) | 0u;   // parity 1, tag 0
  h_ex[i] = 0xFFFEu;                             // parity 0, non-matching tag
}

// ---------------------------------------------------------------------------
// K1: xproj[b,t,:] = inp[b,t,:] @ W_ih  -> rnn slab (overwritten by h later)
// ---------------------------------------------------------------------------
__global__ __launch_bounds__(256) void xproj_kernel(
    const float* __restrict__ inp, const float* __restrict__ W_ih,
    float* __restrict__ rnn) {
  __shared__ float xin[16 * INP];
  const int tid = threadIdx.x;
  const long r0 = (long)blockIdx.x * 16;

  const float4* inp4 = (const float4*)(inp + r0 * INP);
  ((float4*)xin)[tid] = inp4[tid];
  __syncthreads();

  const int j = tid, j2 = tid + 256;
  float acc0[16], acc1[16];
#pragma unroll
  for (int r = 0; r < 16; ++r) { acc0[r] = 0.f; acc1[r] = 0.f; }

  for (int i = 0; i < INP; ++i) {
    const float w0 = W_ih[i * HID + j];
    const float w1 = W_ih[i * HID + j2];
#pragma unroll
    for (int r = 0; r < 16; ++r) {
      const float x = xin[r * INP + i];
      acc0[r] = fmaf(x, w0, acc0[r]);
      acc1[r] = fmaf(x, w1, acc1[r]);
    }
  }
#pragma unroll
  for (int r = 0; r < 16; ++r) {
    rnn[(r0 + r) * HID + j]  = acc0[r];
    rnn[(r0 + r) * HID + j2] = acc1[r];
  }
}

// ---------------------------------------------------------------------------
// K2: recurrence. W_hh register-resident bf16 B-frags. Fence-free tagged-word
// exchange; own-slice cols bypass the LLC round trip via direct LDS writes.
// ---------------------------------------------------------------------------
__global__ __launch_bounds__(512) void rnn_mfma(
    const float* __restrict__ W_hh, float* __restrict__ rnn,
    float* __restrict__ hn_out, uint32_t* __restrict__ h_ex) {
  // [parity][row][col] with row stride 544 shorts (1088 B -> bank shift 16):
  // the 8 distinct b128 read addresses per wave hit 8 distinct bank-quads.
  __shared__ __align__(16) unsigned short hl[2][MROWS][HLPAD];

  const int tid  = threadIdx.x;
  const int lane = tid & 63;
  const int w    = tid >> 6;              // wave 0..7
  const int g    = blockIdx.x & (NGROUP - 1);
  const int s    = blockIdx.x >> 5;       // col-slice 0..3
  const int r0   = g * MROWS;
  const int n_base = s * COLS + w * 16;

  const int lm = lane & 15;               // MFMA m/n lane index
  const int lq = lane >> 4;               // quad 0..3 -> k-subchunk
  const int cc = n_base + lm;             // this lane's output column

  // ---- one-time: W_hh column slice -> bf16 B-frags
  // lane holds B[k = kt*32 + lq*8 + i][n = lm]
  short8 bfrag[16];
#pragma unroll
  for (int kt = 0; kt < 16; ++kt) {
    short8 f;
#pragma unroll
    for (int i = 0; i < 8; ++i) {
      const int k = kt * 32 + lq * 8 + i;
      __hip_bfloat16 hb = __float2bfloat16(W_hh[k * HID + cc]);
      f[i] = *reinterpret_cast<short*>(&hb);
    }
    bfrag[kt] = f;
  }

  const int  arow   = lm & 1;             // A row duplication (M=2 real rows)
  const bool remote = ((tid >> 7) != s);  // col tid outside own slice?
  const bool prod   = (lq == 0);          // producer lanes (hold C rows 0,1)

  // xp double-buffer: producer lanes only
  long ro0 = ((long)r0 * T + 0) * HID + cc;
  long ro1 = ((long)(r0 + 1) * T + 0) * HID + cc;
  float xp0 = 0.f, xp1 = 0.f;
  if (prod) { xp0 = rnn[ro0]; xp1 = rnn[ro1]; }

  for (int t = 0; t < T; ++t) {
    const int p = (t + 1) & 1;            // parity holding h_{t-1}

    // ---- poll tagged words (remote cols; everything at t==0)
    if (t == 0 || remote) {
      uint32_t* src = h_ex + (size_t)p * B * HID + (size_t)r0 * HID + tid;
      const uint32_t want = (uint32_t)t & 0xFFFFu;  // h_{t-1} carries tag t
      uint32_t v0, v1;
      int guard = 0;
      for (;;) {
        v0 = __hip_atomic_load(src, __ATOMIC_RELAXED,
                               __HIP_MEMORY_SCOPE_AGENT);
        v1 = __hip_atomic_load(src + HID, __ATOMIC_RELAXED,
                               __HIP_MEMORY_SCOPE_AGENT);
        if ((((v0 ^ want) | (v1 ^ want)) & 0xFFFFu) == 0) break;
        if (++guard > (1 << 20)) break;   // never hang the harness
      }
      hl[p][0][tid] = (unsigned short)(v0 >> 16);
      hl[p][1][tid] = (unsigned short)(v1 >> 16);
    }
    __syncthreads();                      // one barrier/step (parity dbuf)

    // prefetch next step's xproj (hidden under MFMA + next poll)
    float nxp0 = 0.f, nxp1 = 0.f;
    long nro0 = ro0, nro1 = ro1;
    if (prod && t + 1 < T) {
      nro0 = ro0 + HID; nro1 = ro1 + HID;
      nxp0 = rnn[nro0]; nxp1 = rnn[nro1];
    }

    // ---- 16 MFMA over k, 4 independent chains (depth 4)
    floatx4 c0 = {0.f, 0.f, 0.f, 0.f}, c1 = c0, c2 = c0, c3 = c0;
    const unsigned short* ap = &hl[p][arow][lq * 8];
#pragma unroll
    for (int kt = 0; kt < 16; kt += 4) {
      short8 a0 = *(const short8*)(ap + (kt + 0) * 32);
      short8 a1 = *(const short8*)(ap + (kt + 1) * 32);
      short8 a2 = *(const short8*)(ap + (kt + 2) * 32);
      short8 a3 = *(const short8*)(ap + (kt + 3) * 32);
      c0 = __builtin_amdgcn_mfma_f32_16x16x32_bf16(a0, bfrag[kt + 0], c0, 0, 0, 0);
      c1 = __builtin_amdgcn_mfma_f32_16x16x32_bf16(a1, bfrag[kt + 1], c1, 0, 0, 0);
      c2 = __builtin_amdgcn_mfma_f32_16x16x32_bf16(a2, bfrag[kt + 2], c2, 0, 0, 0);
      c3 = __builtin_amdgcn_mfma_f32_16x16x32_bf16(a3, bfrag[kt + 3], c3, 0, 0, 0);
    }

    if (prod) {  // C layout: col = lane&15, row = (lane>>4)*4 + reg
      const float z0 = c0[0] + c1[0] + c2[0] + c3[0] + xp0;
      const float z1 = c0[1] + c1[1] + c2[1] + c3[1] + xp1;
      const float h0 = 1.f / (1.f + __expf(-z0));
      const float h1 = 1.f / (1.f + __expf(-z1));
      __hip_bfloat16 b0 = __float2bfloat16(h0);
      __hip_bfloat16 b1 = __float2bfloat16(h1);
      const unsigned short u0 = *reinterpret_cast<unsigned short*>(&b0);
      const unsigned short u1 = *reinterpret_cast<unsigned short*>(&b1);

      // critical path first: tagged stores for remote consumers
      const uint32_t tag = (uint32_t)(t + 1) & 0xFFFFu;
      uint32_t* dst = h_ex + (size_t)(t & 1) * B * HID + (size_t)r0 * HID + cc;
      __hip_atomic_store(dst, ((uint32_t)u0 << 16) | tag,
                         __ATOMIC_RELAXED, __HIP_MEMORY_SCOPE_AGENT);
      __hip_atomic_store(dst + HID, ((uint32_t)u1 << 16) | tag,
                         __ATOMIC_RELAXED, __HIP_MEMORY_SCOPE_AGENT);

      // own-slice bypass: stage h_t for our own next step directly in LDS
      hl[t & 1][0][cc] = u0;
      hl[t & 1][1][cc] = u1;

      // non-critical: f32 outputs
      rnn[ro0] = h0;
      rnn[ro1] = h1;
      if (t == T - 1) {
        hn_out[r0 * HID + cc]       = h0;
        hn_out[(r0 + 1) * HID + cc] = h1;
      }
      xp0 = nxp0; xp1 = nxp1; ro0 = nro0; ro1 = nro1;
    }
  }
}

// ---------------------------------------------------------------------------
// K3: out[b,t,:] = sigmoid(rnn[b,t,:] @ W_fc + b_fc)
// ---------------------------------------------------------------------------
__global__ __launch_bounds__(256) void fc_kernel(
    const float* __restrict__ rnn, const float* __restrict__ W_fc,
    const float* __restrict__ b_fc, float* __restrict__ out) {
  const int lane = threadIdx.x & 63;
  const int wid  = threadIdx.x >> 6;
  const long row = (long)blockIdx.x * 4 + wid;

  const float4* __restrict__ hrow = (const float4*)(rnn + row * HID);
  const float4* __restrict__ Wfc4 = (const float4*)W_fc;

  float a0 = 0.f, a1 = 0.f;
#pragma unroll
  for (int u = 0; u < 2; ++u) {
    const float4 hv = hrow[lane * 2 + u];
    const int j0 = lane * 8 + u * 4;
    const float4 wA = Wfc4[(j0 >> 1)];
    const float4 wB = Wfc4[(j0 >> 1) + 1];
    a0 += hv.x * wA.x + hv.y * wA.z + hv.z * wB.x + hv.w * wB.z;
    a1 += hv.x * wA.y + hv.y * wA.w + hv.z * wB.y + hv.w * wB.w;
  }
#pragma unroll
  for (int off = 32; off > 0; off >>= 1) {
    a0 += __shfl_down(a0, off, 64);
    a1 += __shfl_down(a1, off, 64);
  }
  if (lane == 0) {
    out[row * 2 + 0] = 1.f / (1.f + __expf(-(a0 + b_fc[0])));
    out[row * 2 + 1] = 1.f / (1.f + __expf(-(a1 + b_fc[1])));
  }
}

// ---------------------------------------------------------------------------
extern "C" void kernel_launch(void* const* d_in, const int* in_sizes, int n_in,
                              void* d_out, int out_size, void* d_ws,
                              size_t ws_size, hipStream_t stream) {
  const float* inp  = (const float*)d_in[0];
  const float* hn   = (const float*)d_in[1];
  const float* W_hh = (const float*)d_in[2];
  const float* W_ih = (const float*)d_in[3];
  const float* W_fc = (const float*)d_in[4];
  const float* b_fc = (const float*)d_in[5];

  float* out    = (float*)d_out;              // [B,T,ACT]
  float* hn_out = out + (long)B * T * ACT;    // [1,B,HID]
  float* rnn    = hn_out + (long)B * HID;     // [B,T,HID]

  // workspace: h_ex[2][B][HID] tagged uint32 words (256 KB)
  uint32_t* h_ex = (uint32_t*)d_ws;

  hipLaunchKernelGGL(init_kernel, dim3((B * HID) / 256), dim3(256), 0, stream,
                     hn, h_ex);
  hipLaunchKernelGGL(xproj_kernel, dim3((B * T) / 16), dim3(256), 0, stream,
                     inp, W_ih, rnn);
  hipLaunchKernelGGL(rnn_mfma, dim3(NBLOCKS), dim3(512), 0, stream,
                     W_hh, rnn, hn_out, h_ex);
  hipLaunchKernelGGL(fc_kernel, dim3((B * T) / 4), dim3(256), 0, stream,
                     rnn, W_fc, b_fc, out);
}